// Round 10
// baseline (154.607 us; speedup 1.0000x reference)
//
#include <hip/hip_runtime.h>
#include <math.h>

constexpr int D  = 1024;
constexpr int H  = 16;
constexpr int HD = 64;
constexpr int B  = 2;
constexpr int T  = 2048;
constexpr int M  = B * T;   // 4096

constexpr size_t XSZ = (size_t)M * D;   // 4,194,304
constexpr size_t WSZ = (size_t)D * D;   // 1,048,576

typedef float  f32x4   __attribute__((ext_vector_type(4)));
typedef float  f32x16  __attribute__((ext_vector_type(16)));
typedef __bf16 bf16x8  __attribute__((ext_vector_type(8)));
typedef __bf16 bf16x4  __attribute__((ext_vector_type(4)));
typedef unsigned u32x2 __attribute__((ext_vector_type(2)));
typedef unsigned u32x4 __attribute__((ext_vector_type(4)));

static __device__ inline f32x4 mfma16(bf16x8 a, bf16x8 b, f32x4 c) {
  return __builtin_amdgcn_mfma_f32_16x16x32_bf16(a, b, c, 0, 0, 0);
}
static __device__ inline f32x16 mfma32(bf16x8 a, bf16x8 b, f32x16 c) {
  return __builtin_amdgcn_mfma_f32_32x32x16_bf16(a, b, c, 0, 0, 0);
}
// pack two f32 -> u32 of 2 bf16 (lo = a, hi = b); no builtin on gfx950
static __device__ inline unsigned cvtpk(float a, float b) {
  unsigned r;
  asm("v_cvt_pk_bf16_f32 %0, %1, %2" : "=v"(r) : "v"(a), "v"(b));
  return r;
}
static __device__ inline u32x2 plswap(unsigned a, unsigned b) {
  return __builtin_amdgcn_permlane32_swap(a, b, false, false);
}
// async global->LDS, 16B per lane (dest = wave-uniform base + lane*16)
static __device__ inline void gload16(const __bf16* g, __bf16* l) {
  __builtin_amdgcn_global_load_lds(
      (const __attribute__((address_space(1))) void*)g,
      (__attribute__((address_space(3))) void*)l, 16, 0, 0);
}

// ---------------------------------------------------------------------------
// Fused fp32->bf16 convert of x + 4 weights into contiguous bf16 workspace.
// ---------------------------------------------------------------------------
__global__ __launch_bounds__(256)
void cvt_all(const float* __restrict__ x, const float* __restrict__ wq,
             const float* __restrict__ wk, const float* __restrict__ wv,
             const float* __restrict__ wo, __bf16* __restrict__ out) {
  size_t idx = ((size_t)blockIdx.x * 256 + threadIdx.x) * 8;
  const float* src;
  if      (idx < XSZ)            src = x  + idx;
  else if (idx < XSZ + WSZ)      src = wq + (idx - XSZ);
  else if (idx < XSZ + 2 * WSZ)  src = wk + (idx - XSZ - WSZ);
  else if (idx < XSZ + 3 * WSZ)  src = wv + (idx - XSZ - 2 * WSZ);
  else                           src = wo + (idx - XSZ - 3 * WSZ);
  float4 a = *reinterpret_cast<const float4*>(src);
  float4 b = *reinterpret_cast<const float4*>(src + 4);
  bf16x8 o;
  o[0] = (__bf16)a.x; o[1] = (__bf16)a.y; o[2] = (__bf16)a.z; o[3] = (__bf16)a.w;
  o[4] = (__bf16)b.x; o[5] = (__bf16)b.y; o[6] = (__bf16)b.z; o[7] = (__bf16)b.w;
  *reinterpret_cast<bf16x8*>(out + idx) = o;
}

// ---------------------------------------------------------------------------
// MFMA GEMM, global_load_lds staging. C[m,n] = sum_k A[m,k]*W[n,k].
// MODE 1: fused QKV; Q gets softmax-scale (0.125*log2e) folded into RoPE.
// MODE 0: single GEMM (wo), fp32 out.
// ---------------------------------------------------------------------------
template<int MODE>
__global__ __launch_bounds__(512)
void gemm_mfma(const __bf16* __restrict__ A,
               const __bf16* __restrict__ W0, const __bf16* __restrict__ W1,
               const __bf16* __restrict__ W2,
               const float* __restrict__ cosT, const float* __restrict__ sinT,
               void* __restrict__ out0, void* __restrict__ out1,
               void* __restrict__ out2) {
  __shared__ __bf16 As[128 * 64];
  __shared__ __bf16 Bs[128 * 64];

  const int tid  = threadIdx.x;
  const int lane = tid & 63;
  const int w    = tid >> 6;     // 0..7
  const int wm   = w >> 1;       // 0..3 (32 rows each)
  const int wn   = w & 1;        // 0..1 (64 cols each)
  const int l15  = lane & 15, lg = lane >> 4;
  const int m0   = blockIdx.y * 128;

  int which, n0;
  const __bf16* Bw;
  if (MODE == 1) {
    which = blockIdx.x >> 3;
    n0 = (blockIdx.x & 7) * 128;
    Bw = which == 0 ? W0 : which == 1 ? W1 : W2;
  } else {
    which = 0;
    n0 = blockIdx.x * 128;
    Bw = W0;
  }

  f32x4 acc[2][4];
  #pragma unroll
  for (int i = 0; i < 2; ++i)
    #pragma unroll
    for (int j = 0; j < 4; ++j) acc[i][j] = (f32x4){0.f, 0.f, 0.f, 0.f};

  const int e0 = tid * 8;        // 0..4095
  const int r0 = e0 >> 6;        // 0..63
  const int c0 = e0 & 63;

  for (int k0 = 0; k0 < 1024; k0 += 64) {
    const __bf16* ga = A  + (size_t)(m0 + r0) * 1024 + k0 + c0;
    const __bf16* gb = Bw + (size_t)(n0 + r0) * 1024 + k0 + c0;
    gload16(ga,             As + e0);
    gload16(ga + 64 * 1024, As + e0 + 4096);
    gload16(gb,             Bs + e0);
    gload16(gb + 64 * 1024, Bs + e0 + 4096);
    __syncthreads();

    #pragma unroll
    for (int ks = 0; ks < 2; ++ks) {
      bf16x8 af[2], bfr[4];
      #pragma unroll
      for (int mt = 0; mt < 2; ++mt)
        af[mt] = *reinterpret_cast<const bf16x8*>(
            &As[(wm * 32 + mt * 16 + l15) * 64 + ks * 32 + lg * 8]);
      #pragma unroll
      for (int nt = 0; nt < 4; ++nt)
        bfr[nt] = *reinterpret_cast<const bf16x8*>(
            &Bs[(wn * 64 + nt * 16 + l15) * 64 + ks * 32 + lg * 8]);
      #pragma unroll
      for (int mt = 0; mt < 2; ++mt)
        #pragma unroll
        for (int nt = 0; nt < 4; ++nt)
          acc[mt][nt] = mfma16(af[mt], bfr[nt], acc[mt][nt]);
    }
    __syncthreads();
  }

  if (MODE == 0) {
    float* o = (float*)out0;
    #pragma unroll
    for (int mt = 0; mt < 2; ++mt) {
      const int mb = m0 + wm * 32 + mt * 16 + lg * 4;
      #pragma unroll
      for (int nt = 0; nt < 4; ++nt) {
        const int n = n0 + wn * 64 + nt * 16 + l15;
        #pragma unroll
        for (int r = 0; r < 4; ++r)
          o[(size_t)(mb + r) * 1024 + n] = acc[mt][nt][r];
      }
    }
  } else if (which < 2) {
    // Q or K: RoPE fused; Q additionally scaled by 0.125*log2(e).
    __bf16* dst = which == 0 ? (__bf16*)out0 : (__bf16*)out1;
    const float qs = (which == 0) ? 0.180336880f : 1.0f;
    const int h = (n0 + wn * 64) >> 6;
    #pragma unroll
    for (int mt = 0; mt < 2; ++mt) {
      const int tb   = m0 + wm * 32 + mt * 16 + lg * 4;
      const int bb   = tb >> 11;
      const int tloc = tb & 2047;
      #pragma unroll
      for (int r = 0; r < 4; ++r) {
        const int t = tloc + r;
        #pragma unroll
        for (int nt = 0; nt < 2; ++nt) {
          const int hd = nt * 16 + l15;
          const float c = cosT[t * HD + hd];
          const float s = sinT[t * HD + hd];
          const float v1 = acc[mt][nt][r];
          const float v2 = acc[mt][nt + 2][r];
          const size_t base = (((size_t)(bb * H + h)) * T + t) * HD;
          dst[base + hd]      = (__bf16)((v1 * c - v2 * s) * qs);
          dst[base + hd + 32] = (__bf16)((v2 * c + v1 * s) * qs);
        }
      }
    }
  } else {
    // V: transposed store [bh][hd][t]
    __bf16* dst = (__bf16*)out2;
    const int h = (n0 + wn * 64) >> 6;
    #pragma unroll
    for (int mt = 0; mt < 2; ++mt) {
      const int tb = m0 + wm * 32 + mt * 16 + lg * 4;
      const int bb = tb >> 11;
      const int t0 = tb & 2047;
      #pragma unroll
      for (int nt = 0; nt < 4; ++nt) {
        const int hd = nt * 16 + l15;
        bf16x4 ov;
        #pragma unroll
        for (int r = 0; r < 4; ++r) ov[r] = (__bf16)acc[mt][nt][r];
        *reinterpret_cast<bf16x4*>(
            &dst[(((size_t)(bb * H + h)) * HD + hd) * T + t0]) = ov;
      }
    }
  }
}

// ---------------------------------------------------------------------------
// attn_v8: barrier-free, LDS-free, register-pipelined flash attention.
// 256 thr = 4 INDEPENDENT waves; each wave owns one 32-row q-tile and
// iterates 32-key tiles, K/V fragments loaded global->VGPR one tile ahead
// (latency hidden under previous tile's softmax+PV). No s_barrier, no DS ops
// (cross-half via permlane32_swap). In-register softmax, defer-max.
// qt map: wave w of block (x,y): {2x, 63-2x, 2x+1, 62-2x}[w ^ (y>=16)]
//   -> each SIMD's two co-resident waves total exactly 65 tiles.
// Q: [bh][t][64] pre-scaled by 0.125*log2e. K: [bh][t][64]. Vt: [bh][64][t].
// ---------------------------------------------------------------------------
__global__ __launch_bounds__(256, 2)
void attn_v8(const __bf16* __restrict__ Q, const __bf16* __restrict__ K,
             const __bf16* __restrict__ Vt, __bf16* __restrict__ Ob) {
  const int tid  = threadIdx.x;
  const int lane = tid & 63;
  const int w    = tid >> 6;          // 0..3
  const int l31  = lane & 31;
  const int hi   = lane >> 5;         // 0..1
  const int x    = blockIdx.x;        // 0..15
  const int bh   = blockIdx.y;        // 0..31

  const int wi = (bh < 16) ? w : (w ^ 1);
  const int qt = (wi == 0) ? 2 * x : (wi == 1) ? 63 - 2 * x
               : (wi == 2) ? 2 * x + 1 : 62 - 2 * x;
  const int q0w    = qt * 32;
  const int ntiles = qt + 1;

  const __bf16* Qg = Q  + (size_t)bh * T * HD;
  const __bf16* Kg = K  + (size_t)bh * T * HD;
  const __bf16* Vg = Vt + (size_t)bh * HD * T;

  // Q B-fragments: col=q=l31; per k-step st: elements st*16 + hi*8 ..+8
  bf16x8 qfr[4];
  #pragma unroll
  for (int st = 0; st < 4; ++st)
    qfr[st] = *reinterpret_cast<const bf16x8*>(
        Qg + (size_t)(q0w + l31) * HD + st * 16 + hi * 8);

  float m_run = -INFINITY, l_run = 0.f;
  f32x16 oacc0, oacc1;
  #pragma unroll
  for (int i = 0; i < 16; ++i) { oacc0[i] = 0.f; oacc1[i] = 0.f; }

  // K frag (A): row=key=l31, k elems hi*8; V frag (A): row=hd, k elems hi*8
  const __bf16* kbase = Kg + (size_t)l31 * HD + hi * 8;
  const __bf16* vbase = Vg + (size_t)l31 * T + hi * 8;

#define LOADKV(K0, K1, K2, K3, V00, V01, V10, V11, jj)                        \
  do {                                                                        \
    const __bf16* _kp = kbase + (size_t)(jj) * 32 * HD;                       \
    K0 = *reinterpret_cast<const bf16x8*>(_kp);                               \
    K1 = *reinterpret_cast<const bf16x8*>(_kp + 16);                          \
    K2 = *reinterpret_cast<const bf16x8*>(_kp + 32);                          \
    K3 = *reinterpret_cast<const bf16x8*>(_kp + 48);                          \
    const __bf16* _vp = vbase + (size_t)(jj) * 32;                            \
    V00 = *reinterpret_cast<const bf16x8*>(_vp);                              \
    V01 = *reinterpret_cast<const bf16x8*>(_vp + 16);                         \
    V10 = *reinterpret_cast<const bf16x8*>(_vp + (size_t)32 * T);             \
    V11 = *reinterpret_cast<const bf16x8*>(_vp + (size_t)32 * T + 16);        \
  } while (0)

#define TILE(K0, K1, K2, K3, V00, V01, V10, V11, jj)                          \
  do {                                                                        \
    f32x16 sva, svb;                                                          \
    _Pragma("unroll")                                                         \
    for (int _i = 0; _i < 16; ++_i) { sva[_i] = 0.f; svb[_i] = 0.f; }         \
    sva = mfma32(K0, qfr[0], sva);                                            \
    svb = mfma32(K1, qfr[1], svb);                                            \
    sva = mfma32(K2, qfr[2], sva);                                            \
    svb = mfma32(K3, qfr[3], svb);                                            \
    f32x16 sv;                                                                \
    _Pragma("unroll")                                                         \
    for (int _i = 0; _i < 16; ++_i) sv[_i] = sva[_i] + svb[_i];               \
    if ((jj) == qt) { /* diagonal tile: causal mask */                        \
      const int _q = q0w + l31;                                               \
      const int _kb = (jj) * 32 + 4 * hi;                                     \
      _Pragma("unroll")                                                       \
      for (int _r = 0; _r < 16; ++_r) {                                       \
        const int _key = _kb + (_r & 3) + 8 * (_r >> 2);                      \
        if (_key > _q) sv[_r] = -INFINITY;                                    \
      }                                                                       \
    }                                                                         \
    float _mx[8];                                                             \
    _Pragma("unroll")                                                         \
    for (int _i = 0; _i < 8; ++_i) _mx[_i] = fmaxf(sv[_i], sv[_i + 8]);       \
    _Pragma("unroll")                                                         \
    for (int _s = 4; _s > 0; _s >>= 1)                                        \
      _Pragma("unroll")                                                       \
      for (int _i = 0; _i < 4; ++_i)                                          \
        if (_i < _s) _mx[_i] = fmaxf(_mx[_i], _mx[_i + _s]);                  \
    union { float f; unsigned u; } _cv; _cv.f = _mx[0];                       \
    u32x2 _sw = plswap(_cv.u, _cv.u);                                         \
    union { unsigned u; float f; } _c0, _c1; _c0.u = _sw[0]; _c1.u = _sw[1];  \
    const float _pmax = fmaxf(_c0.f, _c1.f);                                  \
    if (__any(_pmax > m_run + 8.f)) {                                         \
      const float _mn = fmaxf(m_run, _pmax);                                  \
      const float _rs = exp2f(m_run - _mn);                                   \
      l_run *= _rs;                                                           \
      _Pragma("unroll")                                                       \
      for (int _i = 0; _i < 16; ++_i) { oacc0[_i] *= _rs; oacc1[_i] *= _rs; } \
      m_run = _mn;                                                            \
    }                                                                         \
    _Pragma("unroll")                                                         \
    for (int _i = 0; _i < 16; ++_i) sv[_i] = exp2f(sv[_i] - m_run);           \
    float _sm[8];                                                             \
    _Pragma("unroll")                                                         \
    for (int _i = 0; _i < 8; ++_i) _sm[_i] = sv[_i] + sv[_i + 8];             \
    _Pragma("unroll")                                                         \
    for (int _s = 4; _s > 0; _s >>= 1)                                        \
      _Pragma("unroll")                                                       \
      for (int _i = 0; _i < 4; ++_i)                                          \
        if (_i < _s) _sm[_i] += _sm[_i + _s];                                 \
    l_run += _sm[0];                                                          \
    unsigned _cp[8];                                                          \
    _Pragma("unroll")                                                         \
    for (int _m = 0; _m < 4; ++_m) {                                          \
      _cp[2 * _m]     = cvtpk(sv[4 * _m],     sv[4 * _m + 1]);                \
      _cp[2 * _m + 1] = cvtpk(sv[4 * _m + 2], sv[4 * _m + 3]);                \
    }                                                                         \
    {                                                                         \
      u32x2 _r0 = plswap(_cp[0], _cp[2]);                                     \
      u32x2 _r1 = plswap(_cp[1], _cp[3]);                                     \
      union { u32x4 u; bf16x8 v; } _pu;                                       \
      _pu.u = (u32x4){_r0[0], _r1[0], _r0[1], _r1[1]};                        \
      oacc0 = mfma32(V00, _pu.v, oacc0);                                      \
      oacc1 = mfma32(V10, _pu.v, oacc1);                                      \
    }                                                                         \
    {                                                                         \
      u32x2 _r0 = plswap(_cp[4], _cp[6]);                                     \
      u32x2 _r1 = plswap(_cp[5], _cp[7]);                                     \
      union { u32x4 u; bf16x8 v; } _pu;                                       \
      _pu.u = (u32x4){_r0[0], _r1[0], _r0[1], _r1[1]};                        \
      oacc0 = mfma32(V01, _pu.v, oacc0);                                      \
      oacc1 = mfma32(V11, _pu.v, oacc1);                                      \
    }                                                                         \
  } while (0)

  bf16x8 kA0, kA1, kA2, kA3, vA00, vA01, vA10, vA11;
  bf16x8 kB0, kB1, kB2, kB3, vB00, vB01, vB10, vB11;

  LOADKV(kA0, kA1, kA2, kA3, vA00, vA01, vA10, vA11, 0);
  int j = 0;
  #pragma unroll 1
  for (;;) {
    if (j + 1 < ntiles)
      LOADKV(kB0, kB1, kB2, kB3, vB00, vB01, vB10, vB11, j + 1);
    TILE(kA0, kA1, kA2, kA3, vA00, vA01, vA10, vA11, j);
    if (j + 1 >= ntiles) break;
    if (j + 2 < ntiles)
      LOADKV(kA0, kA1, kA2, kA3, vA00, vA01, vA10, vA11, j + 2);
    TILE(kB0, kB1, kB2, kB3, vB00, vB01, vB10, vB11, j + 1);
    if (j + 2 >= ntiles) break;
    j += 2;
  }
#undef TILE
#undef LOADKV

  // ---- epilogue: O rows hd = (reg&3)+8*(reg>>2)+4hi, q col = l31 ----
  const float l_tot = l_run + __shfl_xor(l_run, 32);
  const float inv = 1.f / l_tot;
  const int b = bh >> 4, h = bh & 15;
  const int q_abs = q0w + l31;
  const size_t rowbase = ((size_t)(b * T + q_abs)) * 1024 + h * 64;
  #pragma unroll
  for (int rg = 0; rg < 4; ++rg) {
    bf16x4 o0, o1;
    #pragma unroll
    for (int r = 0; r < 4; ++r) {
      o0[r] = (__bf16)(oacc0[rg * 4 + r] * inv);
      o1[r] = (__bf16)(oacc1[rg * 4 + r] * inv);
    }
    *reinterpret_cast<bf16x4*>(&Ob[rowbase + rg * 8 + hi * 4])      = o0;
    *reinterpret_cast<bf16x4*>(&Ob[rowbase + 32 + rg * 8 + hi * 4]) = o1;
  }
}

// ---------------------------------------------------------------------------
extern "C" void kernel_launch(void* const* d_in, const int* in_sizes, int n_in,
                              void* d_out, int out_size, void* d_ws, size_t ws_size,
                              hipStream_t stream) {
  const float* x    = (const float*)d_in[0];
  const float* cosT = (const float*)d_in[1];
  const float* sinT = (const float*)d_in[2];
  // d_in[3] = mask (causal, analytic)
  const float* wq   = (const float*)d_in[4];
  const float* wk   = (const float*)d_in[5];
  const float* wv   = (const float*)d_in[6];
  const float* wo   = (const float*)d_in[7];
  float* out = (float*)d_out;

  __bf16* xb   = (__bf16*)d_ws;
  __bf16* wqb  = xb  + XSZ;
  __bf16* wkb  = wqb + WSZ;
  __bf16* wvb  = wkb + WSZ;
  __bf16* wob  = wvb + WSZ;
  __bf16* Qh   = wob + WSZ;      // [bh][t][hd]  (pre-scaled by 0.125*log2e)
  __bf16* Kh   = Qh  + XSZ;      // [bh][t][hd]
  __bf16* Vth  = Kh  + XSZ;      // [bh][hd][t]
  __bf16* attb = Vth + XSZ;      // [M][1024]

  cvt_all<<<(XSZ + 4 * WSZ) / 8 / 256, 256, 0, stream>>>(x, wq, wk, wv, wo, xb);

  gemm_mfma<1><<<dim3(24, 32), 512, 0, stream>>>(
      xb, wqb, wkb, wvb, cosT, sinT, Qh, Kh, Vth);

  attn_v8<<<dim3(16, 32), 256, 0, stream>>>(Qh, Kh, Vth, attb);

  gemm_mfma<0><<<dim3(8, 32), 512, 0, stream>>>(
      attb, wob, nullptr, nullptr, nullptr, nullptr, out, nullptr, nullptr);
}

// Round 11
// 154.219 us; speedup vs baseline: 1.0025x; 1.0025x over previous
//
#include <hip/hip_runtime.h>
#include <math.h>

constexpr int D  = 1024;
constexpr int H  = 16;
constexpr int HD = 64;
constexpr int B  = 2;
constexpr int T  = 2048;
constexpr int M  = B * T;   // 4096

constexpr size_t XSZ = (size_t)M * D;   // 4,194,304
constexpr size_t WSZ = (size_t)D * D;   // 1,048,576

typedef float  f32x4   __attribute__((ext_vector_type(4)));
typedef float  f32x16  __attribute__((ext_vector_type(16)));
typedef __bf16 bf16x8  __attribute__((ext_vector_type(8)));
typedef __bf16 bf16x4  __attribute__((ext_vector_type(4)));
typedef unsigned u32x2 __attribute__((ext_vector_type(2)));
typedef unsigned u32x4 __attribute__((ext_vector_type(4)));

static __device__ inline f32x4 mfma16(bf16x8 a, bf16x8 b, f32x4 c) {
  return __builtin_amdgcn_mfma_f32_16x16x32_bf16(a, b, c, 0, 0, 0);
}
static __device__ inline f32x16 mfma32(bf16x8 a, bf16x8 b, f32x16 c) {
  return __builtin_amdgcn_mfma_f32_32x32x16_bf16(a, b, c, 0, 0, 0);
}
// pack two f32 -> u32 of 2 bf16 (lo = a, hi = b); no builtin on gfx950
static __device__ inline unsigned cvtpk(float a, float b) {
  unsigned r;
  asm("v_cvt_pk_bf16_f32 %0, %1, %2" : "=v"(r) : "v"(a), "v"(b));
  return r;
}
static __device__ inline u32x2 plswap(unsigned a, unsigned b) {
  return __builtin_amdgcn_permlane32_swap(a, b, false, false);
}
// async global->LDS, 16B per lane (dest = wave-uniform base + lane*16)
static __device__ inline void gload16(const __bf16* g, __bf16* l) {
  __builtin_amdgcn_global_load_lds(
      (const __attribute__((address_space(1))) void*)g,
      (__attribute__((address_space(3))) void*)l, 16, 0, 0);
}

// ---------------------------------------------------------------------------
// Fused fp32->bf16 convert of x + 4 weights into contiguous bf16 workspace.
// ---------------------------------------------------------------------------
__global__ __launch_bounds__(256)
void cvt_all(const float* __restrict__ x, const float* __restrict__ wq,
             const float* __restrict__ wk, const float* __restrict__ wv,
             const float* __restrict__ wo, __bf16* __restrict__ out) {
  size_t idx = ((size_t)blockIdx.x * 256 + threadIdx.x) * 8;
  const float* src;
  if      (idx < XSZ)            src = x  + idx;
  else if (idx < XSZ + WSZ)      src = wq + (idx - XSZ);
  else if (idx < XSZ + 2 * WSZ)  src = wk + (idx - XSZ - WSZ);
  else if (idx < XSZ + 3 * WSZ)  src = wv + (idx - XSZ - 2 * WSZ);
  else                           src = wo + (idx - XSZ - 3 * WSZ);
  float4 a = *reinterpret_cast<const float4*>(src);
  float4 b = *reinterpret_cast<const float4*>(src + 4);
  bf16x8 o;
  o[0] = (__bf16)a.x; o[1] = (__bf16)a.y; o[2] = (__bf16)a.z; o[3] = (__bf16)a.w;
  o[4] = (__bf16)b.x; o[5] = (__bf16)b.y; o[6] = (__bf16)b.z; o[7] = (__bf16)b.w;
  *reinterpret_cast<bf16x8*>(out + idx) = o;
}

// ---------------------------------------------------------------------------
// MFMA GEMM, global_load_lds staging. C[m,n] = sum_k A[m,k]*W[n,k].
// MODE 1: fused QKV; Q gets softmax-scale (0.125*log2e) folded into RoPE.
// MODE 0: single GEMM (wo), fp32 out.
// ---------------------------------------------------------------------------
template<int MODE>
__global__ __launch_bounds__(512)
void gemm_mfma(const __bf16* __restrict__ A,
               const __bf16* __restrict__ W0, const __bf16* __restrict__ W1,
               const __bf16* __restrict__ W2,
               const float* __restrict__ cosT, const float* __restrict__ sinT,
               void* __restrict__ out0, void* __restrict__ out1,
               void* __restrict__ out2) {
  __shared__ __bf16 As[128 * 64];
  __shared__ __bf16 Bs[128 * 64];

  const int tid  = threadIdx.x;
  const int lane = tid & 63;
  const int w    = tid >> 6;     // 0..7
  const int wm   = w >> 1;       // 0..3 (32 rows each)
  const int wn   = w & 1;        // 0..1 (64 cols each)
  const int l15  = lane & 15, lg = lane >> 4;
  const int m0   = blockIdx.y * 128;

  int which, n0;
  const __bf16* Bw;
  if (MODE == 1) {
    which = blockIdx.x >> 3;
    n0 = (blockIdx.x & 7) * 128;
    Bw = which == 0 ? W0 : which == 1 ? W1 : W2;
  } else {
    which = 0;
    n0 = blockIdx.x * 128;
    Bw = W0;
  }

  f32x4 acc[2][4];
  #pragma unroll
  for (int i = 0; i < 2; ++i)
    #pragma unroll
    for (int j = 0; j < 4; ++j) acc[i][j] = (f32x4){0.f, 0.f, 0.f, 0.f};

  const int e0 = tid * 8;        // 0..4095
  const int r0 = e0 >> 6;        // 0..63
  const int c0 = e0 & 63;

  for (int k0 = 0; k0 < 1024; k0 += 64) {
    const __bf16* ga = A  + (size_t)(m0 + r0) * 1024 + k0 + c0;
    const __bf16* gb = Bw + (size_t)(n0 + r0) * 1024 + k0 + c0;
    gload16(ga,             As + e0);
    gload16(ga + 64 * 1024, As + e0 + 4096);
    gload16(gb,             Bs + e0);
    gload16(gb + 64 * 1024, Bs + e0 + 4096);
    __syncthreads();

    #pragma unroll
    for (int ks = 0; ks < 2; ++ks) {
      bf16x8 af[2], bfr[4];
      #pragma unroll
      for (int mt = 0; mt < 2; ++mt)
        af[mt] = *reinterpret_cast<const bf16x8*>(
            &As[(wm * 32 + mt * 16 + l15) * 64 + ks * 32 + lg * 8]);
      #pragma unroll
      for (int nt = 0; nt < 4; ++nt)
        bfr[nt] = *reinterpret_cast<const bf16x8*>(
            &Bs[(wn * 64 + nt * 16 + l15) * 64 + ks * 32 + lg * 8]);
      #pragma unroll
      for (int mt = 0; mt < 2; ++mt)
        #pragma unroll
        for (int nt = 0; nt < 4; ++nt)
          acc[mt][nt] = mfma16(af[mt], bfr[nt], acc[mt][nt]);
    }
    __syncthreads();
  }

  if (MODE == 0) {
    float* o = (float*)out0;
    #pragma unroll
    for (int mt = 0; mt < 2; ++mt) {
      const int mb = m0 + wm * 32 + mt * 16 + lg * 4;
      #pragma unroll
      for (int nt = 0; nt < 4; ++nt) {
        const int n = n0 + wn * 64 + nt * 16 + l15;
        #pragma unroll
        for (int r = 0; r < 4; ++r)
          o[(size_t)(mb + r) * 1024 + n] = acc[mt][nt][r];
      }
    }
  } else if (which < 2) {
    // Q or K: RoPE fused; Q additionally scaled by 0.125*log2(e).
    __bf16* dst = which == 0 ? (__bf16*)out0 : (__bf16*)out1;
    const float qs = (which == 0) ? 0.180336880f : 1.0f;
    const int h = (n0 + wn * 64) >> 6;
    #pragma unroll
    for (int mt = 0; mt < 2; ++mt) {
      const int tb   = m0 + wm * 32 + mt * 16 + lg * 4;
      const int bb   = tb >> 11;
      const int tloc = tb & 2047;
      #pragma unroll
      for (int r = 0; r < 4; ++r) {
        const int t = tloc + r;
        #pragma unroll
        for (int nt = 0; nt < 2; ++nt) {
          const int hd = nt * 16 + l15;
          const float c = cosT[t * HD + hd];
          const float s = sinT[t * HD + hd];
          const float v1 = acc[mt][nt][r];
          const float v2 = acc[mt][nt + 2][r];
          const size_t base = (((size_t)(bb * H + h)) * T + t) * HD;
          dst[base + hd]      = (__bf16)((v1 * c - v2 * s) * qs);
          dst[base + hd + 32] = (__bf16)((v2 * c + v1 * s) * qs);
        }
      }
    }
  } else {
    // V: transposed store [bh][hd][t]
    __bf16* dst = (__bf16*)out2;
    const int h = (n0 + wn * 64) >> 6;
    #pragma unroll
    for (int mt = 0; mt < 2; ++mt) {
      const int tb = m0 + wm * 32 + mt * 16 + lg * 4;
      const int bb = tb >> 11;
      const int t0 = tb & 2047;
      #pragma unroll
      for (int nt = 0; nt < 4; ++nt) {
        const int hd = nt * 16 + l15;
        bf16x4 ov;
        #pragma unroll
        for (int r = 0; r < 4; ++r) ov[r] = (__bf16)acc[mt][nt][r];
        *reinterpret_cast<bf16x4*>(
            &dst[(((size_t)(bb * H + h)) * HD + hd) * T + t0]) = ov;
      }
    }
  }
}

// ---------------------------------------------------------------------------
// attn_v9: v8 + XCD-locality swizzle (T1, bh-keyed).
// v8's flaw: grid (16,32) -> XCD = (y*16+x)%8 = x%8, so every XCD touched all
// 32 bh -> 32MB K/V working set thrashed the 4MB L2 -> L3/HBM latency on
// every K/V fragment (FETCH 79MB). Remap so XCD = bh&7:
//   bh = (bx&7) + 8*(by>>3),  x = (bx>>3) + 2*(by&7)   (bijective)
// -> each XCD serves 4 bh (K+V = 4MB ~ L2). Co-resident blocks (id, id+256)
// still differ by 16 in bh, preserving the 65-tile/SIMD complementary pairing.
// Everything else identical to v8 (no LDS, no barriers, register pipeline).
// ---------------------------------------------------------------------------
__global__ __launch_bounds__(256, 2)
void attn_v9(const __bf16* __restrict__ Q, const __bf16* __restrict__ K,
             const __bf16* __restrict__ Vt, __bf16* __restrict__ Ob) {
  const int tid  = threadIdx.x;
  const int lane = tid & 63;
  const int w    = tid >> 6;          // 0..3
  const int l31  = lane & 31;
  const int hi   = lane >> 5;         // 0..1
  const int bx   = blockIdx.x;        // 0..15
  const int by   = blockIdx.y;        // 0..31
  const int bh   = (bx & 7) + 8 * (by >> 3);   // XCD = bh&7
  const int x    = (bx >> 3) + 2 * (by & 7);   // 0..15

  const int wi = (bh < 16) ? w : (w ^ 1);
  const int qt = (wi == 0) ? 2 * x : (wi == 1) ? 63 - 2 * x
               : (wi == 2) ? 2 * x + 1 : 62 - 2 * x;
  const int q0w    = qt * 32;
  const int ntiles = qt + 1;

  const __bf16* Qg = Q  + (size_t)bh * T * HD;
  const __bf16* Kg = K  + (size_t)bh * T * HD;
  const __bf16* Vg = Vt + (size_t)bh * HD * T;

  // Q B-fragments: col=q=l31; per k-step st: elements st*16 + hi*8 ..+8
  bf16x8 qfr[4];
  #pragma unroll
  for (int st = 0; st < 4; ++st)
    qfr[st] = *reinterpret_cast<const bf16x8*>(
        Qg + (size_t)(q0w + l31) * HD + st * 16 + hi * 8);

  float m_run = -INFINITY, l_run = 0.f;
  f32x16 oacc0, oacc1;
  #pragma unroll
  for (int i = 0; i < 16; ++i) { oacc0[i] = 0.f; oacc1[i] = 0.f; }

  // K frag (A): row=key=l31, k elems hi*8; V frag (A): row=hd, k elems hi*8
  const __bf16* kbase = Kg + (size_t)l31 * HD + hi * 8;
  const __bf16* vbase = Vg + (size_t)l31 * T + hi * 8;

#define LOADKV(K0, K1, K2, K3, V00, V01, V10, V11, jj)                        \
  do {                                                                        \
    const __bf16* _kp = kbase + (size_t)(jj) * 32 * HD;                       \
    K0 = *reinterpret_cast<const bf16x8*>(_kp);                               \
    K1 = *reinterpret_cast<const bf16x8*>(_kp + 16);                          \
    K2 = *reinterpret_cast<const bf16x8*>(_kp + 32);                          \
    K3 = *reinterpret_cast<const bf16x8*>(_kp + 48);                          \
    const __bf16* _vp = vbase + (size_t)(jj) * 32;                            \
    V00 = *reinterpret_cast<const bf16x8*>(_vp);                              \
    V01 = *reinterpret_cast<const bf16x8*>(_vp + 16);                         \
    V10 = *reinterpret_cast<const bf16x8*>(_vp + (size_t)32 * T);             \
    V11 = *reinterpret_cast<const bf16x8*>(_vp + (size_t)32 * T + 16);        \
  } while (0)

#define TILE(K0, K1, K2, K3, V00, V01, V10, V11, jj)                          \
  do {                                                                        \
    f32x16 sva, svb;                                                          \
    _Pragma("unroll")                                                         \
    for (int _i = 0; _i < 16; ++_i) { sva[_i] = 0.f; svb[_i] = 0.f; }         \
    sva = mfma32(K0, qfr[0], sva);                                            \
    svb = mfma32(K1, qfr[1], svb);                                            \
    sva = mfma32(K2, qfr[2], sva);                                            \
    svb = mfma32(K3, qfr[3], svb);                                            \
    f32x16 sv;                                                                \
    _Pragma("unroll")                                                         \
    for (int _i = 0; _i < 16; ++_i) sv[_i] = sva[_i] + svb[_i];               \
    if ((jj) == qt) { /* diagonal tile: causal mask */                        \
      const int _q = q0w + l31;                                               \
      const int _kb = (jj) * 32 + 4 * hi;                                     \
      _Pragma("unroll")                                                       \
      for (int _r = 0; _r < 16; ++_r) {                                       \
        const int _key = _kb + (_r & 3) + 8 * (_r >> 2);                      \
        if (_key > _q) sv[_r] = -INFINITY;                                    \
      }                                                                       \
    }                                                                         \
    float _mx[8];                                                             \
    _Pragma("unroll")                                                         \
    for (int _i = 0; _i < 8; ++_i) _mx[_i] = fmaxf(sv[_i], sv[_i + 8]);       \
    _Pragma("unroll")                                                         \
    for (int _s = 4; _s > 0; _s >>= 1)                                        \
      _Pragma("unroll")                                                       \
      for (int _i = 0; _i < 4; ++_i)                                          \
        if (_i < _s) _mx[_i] = fmaxf(_mx[_i], _mx[_i + _s]);                  \
    union { float f; unsigned u; } _cv; _cv.f = _mx[0];                       \
    u32x2 _sw = plswap(_cv.u, _cv.u);                                         \
    union { unsigned u; float f; } _c0, _c1; _c0.u = _sw[0]; _c1.u = _sw[1];  \
    const float _pmax = fmaxf(_c0.f, _c1.f);                                  \
    if (__any(_pmax > m_run + 8.f)) {                                         \
      const float _mn = fmaxf(m_run, _pmax);                                  \
      const float _rs = exp2f(m_run - _mn);                                   \
      l_run *= _rs;                                                           \
      _Pragma("unroll")                                                       \
      for (int _i = 0; _i < 16; ++_i) { oacc0[_i] *= _rs; oacc1[_i] *= _rs; } \
      m_run = _mn;                                                            \
    }                                                                         \
    _Pragma("unroll")                                                         \
    for (int _i = 0; _i < 16; ++_i) sv[_i] = exp2f(sv[_i] - m_run);           \
    float _sm[8];                                                             \
    _Pragma("unroll")                                                         \
    for (int _i = 0; _i < 8; ++_i) _sm[_i] = sv[_i] + sv[_i + 8];             \
    _Pragma("unroll")                                                         \
    for (int _s = 4; _s > 0; _s >>= 1)                                        \
      _Pragma("unroll")                                                       \
      for (int _i = 0; _i < 4; ++_i)                                          \
        if (_i < _s) _sm[_i] += _sm[_i + _s];                                 \
    l_run += _sm[0];                                                          \
    unsigned _cp[8];                                                          \
    _Pragma("unroll")                                                         \
    for (int _m = 0; _m < 4; ++_m) {                                          \
      _cp[2 * _m]     = cvtpk(sv[4 * _m],     sv[4 * _m + 1]);                \
      _cp[2 * _m + 1] = cvtpk(sv[4 * _m + 2], sv[4 * _m + 3]);                \
    }                                                                         \
    {                                                                         \
      u32x2 _r0 = plswap(_cp[0], _cp[2]);                                     \
      u32x2 _r1 = plswap(_cp[1], _cp[3]);                                     \
      union { u32x4 u; bf16x8 v; } _pu;                                       \
      _pu.u = (u32x4){_r0[0], _r1[0], _r0[1], _r1[1]};                        \
      oacc0 = mfma32(V00, _pu.v, oacc0);                                      \
      oacc1 = mfma32(V10, _pu.v, oacc1);                                      \
    }                                                                         \
    {                                                                         \
      u32x2 _r0 = plswap(_cp[4], _cp[6]);                                     \
      u32x2 _r1 = plswap(_cp[5], _cp[7]);                                     \
      union { u32x4 u; bf16x8 v; } _pu;                                       \
      _pu.u = (u32x4){_r0[0], _r1[0], _r0[1], _r1[1]};                        \
      oacc0 = mfma32(V01, _pu.v, oacc0);                                      \
      oacc1 = mfma32(V11, _pu.v, oacc1);                                      \
    }                                                                         \
  } while (0)

  bf16x8 kA0, kA1, kA2, kA3, vA00, vA01, vA10, vA11;
  bf16x8 kB0, kB1, kB2, kB3, vB00, vB01, vB10, vB11;

  LOADKV(kA0, kA1, kA2, kA3, vA00, vA01, vA10, vA11, 0);
  int j = 0;
  #pragma unroll 1
  for (;;) {
    if (j + 1 < ntiles)
      LOADKV(kB0, kB1, kB2, kB3, vB00, vB01, vB10, vB11, j + 1);
    TILE(kA0, kA1, kA2, kA3, vA00, vA01, vA10, vA11, j);
    if (j + 1 >= ntiles) break;
    if (j + 2 < ntiles)
      LOADKV(kA0, kA1, kA2, kA3, vA00, vA01, vA10, vA11, j + 2);
    TILE(kB0, kB1, kB2, kB3, vB00, vB01, vB10, vB11, j + 1);
    if (j + 2 >= ntiles) break;
    j += 2;
  }
#undef TILE
#undef LOADKV

  // ---- epilogue: O rows hd = (reg&3)+8*(reg>>2)+4hi, q col = l31 ----
  const float l_tot = l_run + __shfl_xor(l_run, 32);
  const float inv = 1.f / l_tot;
  const int b = bh >> 4, h = bh & 15;
  const int q_abs = q0w + l31;
  const size_t rowbase = ((size_t)(b * T + q_abs)) * 1024 + h * 64;
  #pragma unroll
  for (int rg = 0; rg < 4; ++rg) {
    bf16x4 o0, o1;
    #pragma unroll
    for (int r = 0; r < 4; ++r) {
      o0[r] = (__bf16)(oacc0[rg * 4 + r] * inv);
      o1[r] = (__bf16)(oacc1[rg * 4 + r] * inv);
    }
    *reinterpret_cast<bf16x4*>(&Ob[rowbase + rg * 8 + hi * 4])      = o0;
    *reinterpret_cast<bf16x4*>(&Ob[rowbase + 32 + rg * 8 + hi * 4]) = o1;
  }
}

// ---------------------------------------------------------------------------
extern "C" void kernel_launch(void* const* d_in, const int* in_sizes, int n_in,
                              void* d_out, int out_size, void* d_ws, size_t ws_size,
                              hipStream_t stream) {
  const float* x    = (const float*)d_in[0];
  const float* cosT = (const float*)d_in[1];
  const float* sinT = (const float*)d_in[2];
  // d_in[3] = mask (causal, analytic)
  const float* wq   = (const float*)d_in[4];
  const float* wk   = (const float*)d_in[5];
  const float* wv   = (const float*)d_in[6];
  const float* wo   = (const float*)d_in[7];
  float* out = (float*)d_out;

  __bf16* xb   = (__bf16*)d_ws;
  __bf16* wqb  = xb  + XSZ;
  __bf16* wkb  = wqb + WSZ;
  __bf16* wvb  = wkb + WSZ;
  __bf16* wob  = wvb + WSZ;
  __bf16* Qh   = wob + WSZ;      // [bh][t][hd]  (pre-scaled by 0.125*log2e)
  __bf16* Kh   = Qh  + XSZ;      // [bh][t][hd]
  __bf16* Vth  = Kh  + XSZ;      // [bh][hd][t]
  __bf16* attb = Vth + XSZ;      // [M][1024]

  cvt_all<<<(XSZ + 4 * WSZ) / 8 / 256, 256, 0, stream>>>(x, wq, wk, wv, wo, xb);

  gemm_mfma<1><<<dim3(24, 32), 512, 0, stream>>>(
      xb, wqb, wkb, wvb, cosT, sinT, Qh, Kh, Vth);

  attn_v9<<<dim3(16, 32), 256, 0, stream>>>(Qh, Kh, Vth, attb);

  gemm_mfma<0><<<dim3(8, 32), 512, 0, stream>>>(
      attb, wob, nullptr, nullptr, nullptr, nullptr, out, nullptr, nullptr);
}